// Round 9
// baseline (934.328 us; speedup 1.0000x reference)
//
#include <hip/hip_runtime.h>
#include <cmath>

// Problem constants
// B=8, C=256, H=W=64, HW=4096, NT=32768 tokens
// heads M=8, head dim D=32, regions NR=64 (8x8 of 8x8), RSQ=64, TOPK=4, KSEL=32

typedef __bf16 bf16x8 __attribute__((ext_vector_type(8)));
typedef __bf16 bf16x4 __attribute__((ext_vector_type(4)));
typedef float f32x4 __attribute__((ext_vector_type(4)));
typedef float f32x2 __attribute__((ext_vector_type(2)));

__device__ __forceinline__ void async_copy16(const __bf16* g, __bf16* l) {
  __builtin_amdgcn_global_load_lds(
      (const __attribute__((address_space(1))) void*)g,
      (__attribute__((address_space(3))) void*)l, 16, 0, 0);
}

// ---------------------------------------------------------------------------
// Tiled transpose: per batch, src [R][Cc] -> dst [Cc][R]. 64x64 tiles.
// (input NCHW->NHWC only; output written NCHW by mlp2 epilogue)
// ---------------------------------------------------------------------------
__global__ __launch_bounds__(256) void transpose_kernel(
    const float* __restrict__ src, float* __restrict__ dst, int R, int Cc) {
  __shared__ float T[64][65];
  int b = blockIdx.z;
  int r0 = blockIdx.y * 64, c0 = blockIdx.x * 64;
  const float* S = src + (size_t)b * R * Cc;
  float* D = dst + (size_t)b * R * Cc;
  int lane = threadIdx.x & 63, wq = threadIdx.x >> 6;
#pragma unroll
  for (int j = 0; j < 16; j++) {
    int rr = wq + j * 4;
    T[rr][lane] = S[(size_t)(r0 + rr) * Cc + c0 + lane];
  }
  __syncthreads();
#pragma unroll
  for (int j = 0; j < 16; j++) {
    int cc = wq + j * 4;
    D[(size_t)(c0 + cc) * R + r0 + lane] = T[lane][cc];
  }
}

// ---------------------------------------------------------------------------
// K1: xa = xt + dwconv3x3(xt,pos), all NHWC.
// ---------------------------------------------------------------------------
__global__ __launch_bounds__(256) void posconv_kernel(
    const float* __restrict__ xt, const float* __restrict__ pw,
    const float* __restrict__ pb, float* __restrict__ xa) {
  __shared__ float Ls[100][64];
  __shared__ float Ws[9][64];
  int blk = blockIdx.x;  // 8*64*4
  int b = blk >> 8, r = (blk >> 2) & 63, cg = blk & 3;
  int h0 = (r >> 3) << 3, w0 = (r & 7) << 3;
  int c0 = cg << 6;
  int tid = threadIdx.x, cl = tid & 63;
  const float* src = xt + ((size_t)b * 4096) * 256;
  for (int i = tid; i < 6400; i += 256) {
    int pos = i >> 6, ccl = i & 63;
    int hh = h0 + (pos / 10) - 1, ww = w0 + (pos % 10) - 1;
    float val = 0.f;
    if (hh >= 0 && hh < 64 && ww >= 0 && ww < 64)
      val = src[(size_t)(hh * 64 + ww) * 256 + c0 + ccl];
    Ls[pos][ccl] = val;
  }
  for (int i = tid; i < 576; i += 256) {
    int tap = i >> 6, ccl = i & 63;
    Ws[tap][ccl] = pw[(c0 + ccl) * 9 + tap];
  }
  __syncthreads();
  float bias = pb[c0 + cl];
  for (int j = 0; j < 16; j++) {
    int p = (tid >> 6) + (j << 2);
    int ph = p >> 3, pww = p & 7;
    float acc = bias;
#pragma unroll
    for (int dh = 0; dh < 3; dh++)
#pragma unroll
      for (int dw = 0; dw < 3; dw++)
        acc += Ls[(ph + dh) * 10 + (pww + dw)][cl] * Ws[dh * 3 + dw][cl];
    float xv = Ls[(ph + 1) * 10 + (pww + 1)][cl];
    xa[((size_t)(b * 4096 + (h0 + ph) * 64 + (w0 + pww))) * 256 + c0 + cl] =
        xv + acc;
  }
}

// ---------------------------------------------------------------------------
// LayerNorm over C=256, one wave per token, bf16 output (GEMM A operand)
// ---------------------------------------------------------------------------
__global__ __launch_bounds__(64) void ln_kernel(
    const float* __restrict__ in, const float* __restrict__ g,
    const float* __restrict__ bb, __bf16* __restrict__ out) {
  int t = blockIdx.x; int l = threadIdx.x;
  const float* p = in + (size_t)t * 256;
  float v0 = p[l], v1 = p[l + 64], v2 = p[l + 128], v3 = p[l + 192];
  float s = v0 + v1 + v2 + v3;
#pragma unroll
  for (int off = 32; off; off >>= 1) s += __shfl_xor(s, off);
  float mu = s * (1.f / 256.f);
  float d0 = v0 - mu, d1 = v1 - mu, d2 = v2 - mu, d3 = v3 - mu;
  float sq = d0 * d0 + d1 * d1 + d2 * d2 + d3 * d3;
#pragma unroll
  for (int off = 32; off; off >>= 1) sq += __shfl_xor(sq, off);
  float rstd = rsqrtf(sq * (1.f / 256.f) + 1e-6f);
  __bf16* o = out + (size_t)t * 256;
  o[l]       = (__bf16)(d0 * rstd * g[l]       + bb[l]);
  o[l + 64]  = (__bf16)(d1 * rstd * g[l + 64]  + bb[l + 64]);
  o[l + 128] = (__bf16)(d2 * rstd * g[l + 128] + bb[l + 128]);
  o[l + 192] = (__bf16)(d3 * rstd * g[l + 192] + bb[l + 192]);
}

// ---------------------------------------------------------------------------
// Weight prep: bf16-convert qkv_w [768][256], out_w [256][256] (already [N][K]),
// transpose+convert mlp_w1 [256][768]->[768][256], mlp_w2 [768][256]->[256][768]
// ---------------------------------------------------------------------------
__global__ __launch_bounds__(256) void wprep_kernel(
    const float* __restrict__ qkv_w, const float* __restrict__ out_w,
    const float* __restrict__ w1, const float* __restrict__ w2,
    __bf16* __restrict__ wq, __bf16* __restrict__ wo,
    __bf16* __restrict__ w1t, __bf16* __restrict__ w2t) {
  int i = blockIdx.x * 256 + threadIdx.x;
  if (i < 196608) wq[i] = (__bf16)qkv_w[i];
  if (i < 65536) wo[i] = (__bf16)out_w[i];
  if (i < 196608) {  // w1t[n][k] = w1[k][n], n<768, k<256
    int n = i >> 8, k2 = i & 255;
    w1t[i] = (__bf16)w1[k2 * 768 + n];
  }
  if (i < 196608) {  // w2t[n][k] = w2[k][n], n<256, k<768
    int n = i / 768, k2 = i % 768;
    w2t[i] = (__bf16)w2[k2 * 256 + n];
  }
}

// ---------------------------------------------------------------------------
// MFMA bf16 GEMM: C[row][col] = epi( sum_k A[row][k]*Bw[col][k] + bias[col] )
// A [M][K] bf16, Bw [N][K] bf16. 128x128 tile, BK=32, 4 waves (2x2 quadrants),
// global_load_lds width-16 staging, mfma_f32_16x16x32_bf16.
// EPI: 0 = scatter to q(fp32)/k,v(bf16) seq layout; 1 = fp32 res+val;
//      2 = gelu -> bf16; 3 = res+val written NCHW fp32 (fused transpose)
// ---------------------------------------------------------------------------
template <int EPI>
__global__ __launch_bounds__(256) void mfma_gemm(
    const __bf16* __restrict__ A, const __bf16* __restrict__ Bw,
    const float* __restrict__ bias, const float* __restrict__ res,
    float* __restrict__ out, __bf16* __restrict__ outb,
    float* __restrict__ qd, __bf16* __restrict__ kd, __bf16* __restrict__ vd,
    int N, int K, int row0) {
  __shared__ __bf16 Asl[128 * 32];
  __shared__ __bf16 Bsl[128 * 32];
  int tid = threadIdx.x;
  int lane = tid & 63, wave = tid >> 6;
  int m0 = blockIdx.y * 128, n0 = blockIdx.x * 128;
  int wr = (wave >> 1) * 64, wc = (wave & 1) * 64;

  f32x4 acc[4][4];
  f32x4 z = {0.f, 0.f, 0.f, 0.f};
#pragma unroll
  for (int i = 0; i < 4; i++)
#pragma unroll
    for (int j = 0; j < 4; j++) acc[i][j] = z;

  int srow = (lane >> 2);          // 0..15
  int skoff = (lane & 3) * 8;      // 0,8,16,24
  for (int k0 = 0; k0 < K; k0 += 32) {
#pragma unroll
    for (int j = 0; j < 2; j++) {
      int rbase = wave * 32 + j * 16;
      const __bf16* ga = A + (size_t)(m0 + rbase + srow) * K + k0 + skoff;
      const __bf16* gb = Bw + (size_t)(n0 + rbase + srow) * K + k0 + skoff;
      async_copy16(ga, &Asl[rbase * 32]);
      async_copy16(gb, &Bsl[rbase * 32]);
    }
    __syncthreads();
    bf16x8 af[4], bf[4];
#pragma unroll
    for (int t = 0; t < 4; t++) {
      af[t] = *(const bf16x8*)&Asl[(wr + t * 16 + (lane & 15)) * 32 + (lane >> 4) * 8];
      bf[t] = *(const bf16x8*)&Bsl[(wc + t * 16 + (lane & 15)) * 32 + (lane >> 4) * 8];
    }
#pragma unroll
    for (int ti = 0; ti < 4; ti++)
#pragma unroll
      for (int tj = 0; tj < 4; tj++)
        acc[ti][tj] = __builtin_amdgcn_mfma_f32_16x16x32_bf16(
            af[ti], bf[tj], acc[ti][tj], 0, 0, 0);
    __syncthreads();
  }
  // epilogue: C/D layout col=lane&15, row=(lane>>4)*4+reg
#pragma unroll
  for (int ti = 0; ti < 4; ti++) {
#pragma unroll
    for (int tj = 0; tj < 4; tj++) {
      int colg = n0 + wc + tj * 16 + (lane & 15);
      float bv = bias[colg];
#pragma unroll
      for (int reg = 0; reg < 4; reg++) {
        int rowg = m0 + wr + ti * 16 + (lane >> 4) * 4 + reg;
        float val = acc[ti][tj][reg] + bv;
        if (EPI == 0) {
          int tns = colg >> 8, cc = colg & 255, m = cc >> 5, d = cc & 31;
          int grow = row0 + rowg;
          int b = grow >> 12, hw = grow & 4095, h = hw >> 6, w = hw & 63;
          int r = ((h >> 3) << 3) | (w >> 3), s2 = ((h & 7) << 3) | (w & 7);
          size_t addr = (size_t)(b * 8 + m) * 131072 + r * 2048 + s2 * 32 + d;
          if (tns == 0) qd[addr] = val;
          else if (tns == 1) kd[addr] = (__bf16)val;
          else vd[addr] = (__bf16)val;
        } else if (EPI == 1) {
          out[(size_t)rowg * N + colg] = res[(size_t)rowg * N + colg] + val;
        } else if (EPI == 2) {
          outb[(size_t)rowg * N + colg] =
              (__bf16)(0.5f * val * (1.f + erff(val * 0.70710678118654752f)));
        } else {
          int grow = row0 + rowg;
          int b = grow >> 12, hw = grow & 4095;
          out[(size_t)(b * 256 + colg) * 4096 + hw] =
              res[(size_t)grow * 256 + colg] + val;
        }
      }
    }
  }
}

// ---------------------------------------------------------------------------
// Routing path, fp32-exact via linearity: region-mean of LN1 recomputed from
// xa (fp32), then q_r/k_r = qkv_w @ lnmean + bias. Matches reference top-4.
// ---------------------------------------------------------------------------
__global__ __launch_bounds__(256) void lnmean_kernel(
    const float* __restrict__ xa, const float* __restrict__ g,
    const float* __restrict__ bb, float* __restrict__ lnm) {
  __shared__ float part[4][256];
  int br = blockIdx.x; int b = br >> 6, r = br & 63;
  int h0 = (r >> 3) << 3, w0 = (r & 7) << 3;
  int wave = threadIdx.x >> 6, l = threadIdx.x & 63;
  float a0 = 0.f, a1 = 0.f, a2 = 0.f, a3 = 0.f;
  for (int t = wave; t < 64; t += 4) {
    int h = h0 + (t >> 3), w = w0 + (t & 7);
    const float* p = xa + ((size_t)(b * 4096 + h * 64 + w)) * 256;
    float v0 = p[l], v1 = p[l + 64], v2 = p[l + 128], v3 = p[l + 192];
    float s = v0 + v1 + v2 + v3;
#pragma unroll
    for (int off = 32; off; off >>= 1) s += __shfl_xor(s, off);
    float mu = s * (1.f / 256.f);
    float d0 = v0 - mu, d1 = v1 - mu, d2 = v2 - mu, d3 = v3 - mu;
    float sq = d0 * d0 + d1 * d1 + d2 * d2 + d3 * d3;
#pragma unroll
    for (int off = 32; off; off >>= 1) sq += __shfl_xor(sq, off);
    float rstd = rsqrtf(sq * (1.f / 256.f) + 1e-6f);
    a0 += d0 * rstd; a1 += d1 * rstd; a2 += d2 * rstd; a3 += d3 * rstd;
  }
  part[wave][l] = a0; part[wave][l + 64] = a1;
  part[wave][l + 128] = a2; part[wave][l + 192] = a3;
  __syncthreads();
  if (wave == 0) {
    for (int c = l; c < 256; c += 64) {
      float s2 = part[0][c] + part[1][c] + part[2][c] + part[3][c];
      lnm[(size_t)br * 256 + c] = g[c] * (s2 * (1.f / 64.f)) + bb[c];
    }
  }
}

__global__ __launch_bounds__(256) void qkr_kernel(
    const float* __restrict__ lnm, const float* __restrict__ qkv_w,
    const float* __restrict__ qkv_b, float* __restrict__ qr,
    float* __restrict__ kr) {
  __shared__ float xm[256];
  int br = blockIdx.x, c = threadIdx.x;
  xm[c] = lnm[(size_t)br * 256 + c];
  __syncthreads();
  const float* wqp = qkv_w + (size_t)c * 256;
  const float* wkp = qkv_w + (size_t)(256 + c) * 256;
  float aq = 0.f, ak = 0.f;
  for (int k2 = 0; k2 < 256; k2++) {
    float xv = xm[k2];
    aq += wqp[k2] * xv; ak += wkp[k2] * xv;
  }
  qr[(size_t)br * 256 + c] = aq + qkv_b[c];
  kr[(size_t)br * 256 + c] = ak + qkv_b[256 + c];
}

// ---------------------------------------------------------------------------
// R2: a_r = q_r @ k_r^T per batch; top-4 regions per row (jax tie: lower idx)
// ---------------------------------------------------------------------------
__global__ __launch_bounds__(256) void routing_kernel(
    const float* __restrict__ qr, const float* __restrict__ kr,
    int* __restrict__ idxout) {
  __shared__ float Ar[64 * 64];
  int b = blockIdx.x; int tid = threadIdx.x;
  int i = tid >> 2, jg = tid & 3;
  const float* qrow = qr + (size_t)(b * 64 + i) * 256;
  for (int jj = 0; jj < 16; jj++) {
    int j = jg * 16 + jj;
    const float* krow = kr + (size_t)(b * 64 + j) * 256;
    float acc = 0.f;
    for (int c = 0; c < 256; c++) acc += qrow[c] * krow[c];
    Ar[i * 64 + j] = acc;
  }
  __syncthreads();
  if (tid < 64) {
    float v0 = -INFINITY, v1 = -INFINITY, v2 = -INFINITY, v3 = -INFINITY;
    int i0 = 0, i1 = 0, i2 = 0, i3 = 0;
    for (int j = 0; j < 64; j++) {
      float s = Ar[tid * 64 + j];
      if (s > v0)      { v3=v2;i3=i2; v2=v1;i2=i1; v1=v0;i1=i0; v0=s;i0=j; }
      else if (s > v1) { v3=v2;i3=i2; v2=v1;i2=i1; v1=s;i1=j; }
      else if (s > v2) { v3=v2;i3=i2; v2=s;i2=j; }
      else if (s > v3) { v3=s;i3=j; }
    }
    int* op = idxout + (b * 64 + tid) * 4;
    op[0] = i0; op[1] = i1; op[2] = i2; op[3] = i3;
  }
}

// ---------------------------------------------------------------------------
// Attention per (b,m,r): 256 gathered keys (bf16), top-32 per row via
// wave-ballot radix-select on 16-bit keys (proven config, absmax 0.031).
// Scores via packed f32x2 math. Softmax shifted by 16-bit tie-class bound.
// LDS 35 KB. launch_bounds(256,4): VGPR budget 512/4=128, current use 124
// -> should fit with NO spill; goal is 4 blocks/CU resident (was 2 at
// (256,2), OccupancyPercent 22%). Watch FETCH_SIZE for spill signature.
// ---------------------------------------------------------------------------
__global__ __launch_bounds__(256, 4) void attn_kernel(
    float* __restrict__ qio, const __bf16* __restrict__ kbuf,
    const __bf16* __restrict__ vbuf, const int* __restrict__ idx) {
  __shared__ __bf16 Ks[256 * 32];
  __shared__ __bf16 Vs[256 * 32];
  __shared__ float wbuf[4][4][32];
  __shared__ unsigned short cbuf[4][4][32];
  int blk = blockIdx.x; int r = blk & 63; int m = (blk >> 6) & 7; int b = blk >> 9;
  int tid = threadIdx.x;
  int lane = tid & 63, wave = tid >> 6;
  const int* ip = idx + (b * 64 + r) * 4;
  int rg0 = ip[0], rg1 = ip[1], rg2 = ip[2], rg3 = ip[3];
  size_t bm = (size_t)(b * 8 + m) * 131072;

  {
    int rgs[4] = {rg0, rg1, rg2, rg3};
    int s = tid >> 2, g8 = tid & 3;
#pragma unroll
    for (int t = 0; t < 4; t++) {
      const uint4* sk = (const uint4*)(kbuf + bm + rgs[t] * 2048);
      const uint4* sv = (const uint4*)(vbuf + bm + rgs[t] * 2048);
      int kk = (t << 6) | s;
      uint4 kw = sk[tid];
      uint4 vw = sv[tid];
      int dg0 = g8 * 2, dg1 = dg0 + 1;
      uint2 lo; lo.x = kw.x; lo.y = kw.y;
      uint2 hi; hi.x = kw.z; hi.y = kw.w;
      *(uint2*)&Ks[(kk << 5) + (((dg0 + (kk >> 1)) & 7) << 2)] = lo;
      *(uint2*)&Ks[(kk << 5) + (((dg1 + (kk >> 1)) & 7) << 2)] = hi;
      *(uint4*)&Vs[(kk << 5) + (g8 << 3)] = vw;
    }
  }
  __syncthreads();

  const float* qb = qio + bm + r * 2048;
  const float scale = 1.f / 16.f;  // C^-0.5

  for (int g = 0; g < 4; g++) {
    int row0 = (wave << 4) | (g << 2);
    f32x2 sc2[4][4];
    f32x2 z2 = {0.f, 0.f};
#pragma unroll
    for (int i = 0; i < 4; i++)
#pragma unroll
      for (int t = 0; t < 4; t++) sc2[i][t] = z2;
    const f32x2* qp0 = (const f32x2*)(qb + (row0 + 0) * 32);
    const f32x2* qp1 = (const f32x2*)(qb + (row0 + 1) * 32);
    const f32x2* qp2 = (const f32x2*)(qb + (row0 + 2) * 32);
    const f32x2* qp3 = (const f32x2*)(qb + (row0 + 3) * 32);
#pragma unroll
    for (int dg = 0; dg < 8; dg++) {
      f32x2 q0a = qp0[dg * 2], q0b = qp0[dg * 2 + 1];
      f32x2 q1a = qp1[dg * 2], q1b = qp1[dg * 2 + 1];
      f32x2 q2a = qp2[dg * 2], q2b = qp2[dg * 2 + 1];
      f32x2 q3a = qp3[dg * 2], q3b = qp3[dg * 2 + 1];
#pragma unroll
      for (int t = 0; t < 4; t++) {
        int kk = (t << 6) | lane;
        const unsigned* kp =
            (const unsigned*)&Ks[(kk << 5) | (((dg + (kk >> 1)) & 7) << 2)];
        unsigned lo = kp[0], hi = kp[1];
        f32x2 kxy, kzw;
        kxy.x = __uint_as_float(lo << 16);
        kxy.y = __uint_as_float(lo & 0xffff0000u);
        kzw.x = __uint_as_float(hi << 16);
        kzw.y = __uint_as_float(hi & 0xffff0000u);
        sc2[0][t] = sc2[0][t] + q0a * kxy + q0b * kzw;
        sc2[1][t] = sc2[1][t] + q1a * kxy + q1b * kzw;
        sc2[2][t] = sc2[2][t] + q2a * kxy + q2b * kzw;
        sc2[3][t] = sc2[3][t] + q3a * kxy + q3b * kzw;
      }
    }
    // horizontal add + scale, then 16-bit monotone key
    float sc[4][4];
    unsigned uk[4][4];
#pragma unroll
    for (int i = 0; i < 4; i++)
#pragma unroll
      for (int t = 0; t < 4; t++) {
        float v = (sc2[i][t].x + sc2[i][t].y) * scale;
        sc[i][t] = v;
        unsigned bu = __float_as_uint(v);
        uk[i][t] = (bu ^ (unsigned)(((int)bu >> 31) | 0x80000000)) >> 16;
      }
    unsigned p0 = 0, p1 = 0, p2 = 0, p3 = 0;
    for (int bit = 15; bit >= 0; --bit) {
      unsigned msk = 1u << bit;
      unsigned c0 = p0 | msk, c1 = p1 | msk, c2 = p2 | msk, c3 = p3 | msk;
      int n0 = __popcll(__ballot(uk[0][0] >= c0)) + __popcll(__ballot(uk[0][1] >= c0)) +
               __popcll(__ballot(uk[0][2] >= c0)) + __popcll(__ballot(uk[0][3] >= c0));
      int n1 = __popcll(__ballot(uk[1][0] >= c1)) + __popcll(__ballot(uk[1][1] >= c1)) +
               __popcll(__ballot(uk[1][2] >= c1)) + __popcll(__ballot(uk[1][3] >= c1));
      int n2 = __popcll(__ballot(uk[2][0] >= c2)) + __popcll(__ballot(uk[2][1] >= c2)) +
               __popcll(__ballot(uk[2][2] >= c2)) + __popcll(__ballot(uk[2][3] >= c2));
      int n3 = __popcll(__ballot(uk[3][0] >= c3)) + __popcll(__ballot(uk[3][1] >= c3)) +
               __popcll(__ballot(uk[3][2] >= c3)) + __popcll(__ballot(uk[3][3] >= c3));
      if (n0 >= 32) p0 = c0;
      if (n1 >= 32) p1 = c1;
      if (n2 >= 32) p2 = c2;
      if (n3 >= 32) p3 = c3;
    }
    unsigned pr[4] = {p0, p1, p2, p3};
#pragma unroll
    for (int i = 0; i < 4; i++) {
      unsigned T = pr[i];
      unsigned ub = T << 16;  // lower bound of the 16-bit tie class
      unsigned tb = (ub & 0x80000000u) ? (ub ^ 0x80000000u) : ~ub;
      float Tv = __uint_as_float(tb);
      unsigned long long gb[4], eb[4];
#pragma unroll
      for (int t = 0; t < 4; t++) {
        gb[t] = __ballot(uk[i][t] > T);
        eb[t] = __ballot(uk[i][t] == T);
      }
      int bg1 = __popcll(gb[0]), bg2 = bg1 + __popcll(gb[1]), bg3 = bg2 + __popcll(gb[2]);
      int cgt = bg3 + __popcll(gb[3]);
      int be1 = __popcll(eb[0]), be2 = be1 + __popcll(eb[1]), be3 = be2 + __popcll(eb[2]);
      int need = 32 - cgt;
      int bgs[4] = {0, bg1, bg2, bg3};
      int bes[4] = {0, be1, be2, be3};
#pragma unroll
      for (int t = 0; t < 4; t++) {
        int rgt = bgs[t] + __builtin_amdgcn_mbcnt_hi(
                               (unsigned)(gb[t] >> 32),
                               __builtin_amdgcn_mbcnt_lo((unsigned)gb[t], 0));
        int ret = bes[t] + __builtin_amdgcn_mbcnt_hi(
                               (unsigned)(eb[t] >> 32),
                               __builtin_amdgcn_mbcnt_lo((unsigned)eb[t], 0));
        bool isg = uk[i][t] > T;
        bool sel = isg || (uk[i][t] == T && ret < need);
        int slot = isg ? rgt : (cgt + ret);
        if (sel) {
          wbuf[wave][i][slot] = __expf(sc[i][t] - Tv);
          cbuf[wave][i][slot] = (unsigned short)((t << 6) | lane);
        }
      }
    }
#pragma unroll
    for (int i = 0; i < 4; i++) {
      int dd = lane & 31, half = lane >> 5;
      float acc = 0.f, wsum = 0.f;
#pragma unroll
      for (int it2 = 0; it2 < 16; it2++) {
        int sl = (half << 4) | it2;
        float wi = wbuf[wave][i][sl];
        int ci = cbuf[wave][i][sl];
        acc += wi * (float)Vs[(ci << 5) | dd];
        wsum += wi;
      }
      acc += __shfl_xor(acc, 32);
      wsum += __shfl_xor(wsum, 32);
      if (lane < 32) qio[bm + r * 2048 + (row0 + i) * 32 + dd] = acc / wsum;
    }
  }
}

// ---------------------------------------------------------------------------
// K6: t = seq2grid(attn_out) + dwconv5x5(v) + lepe_b, NHWC bf16 out.
// ---------------------------------------------------------------------------
__global__ __launch_bounds__(256) void lepe_kernel(
    const float* __restrict__ ao, const __bf16* __restrict__ v,
    const float* __restrict__ lw, const float* __restrict__ lb,
    __bf16* __restrict__ tout) {
  __shared__ float Ls[144][32];
  __shared__ float Ws[25][32];
  int blk = blockIdx.x;  // 8*8*64
  int b = blk >> 9, m = (blk >> 6) & 7, r = blk & 63;
  int h0 = (r >> 3) << 3, w0 = (r & 7) << 3;
  int tid = threadIdx.x, d = tid & 31;
  size_t bm = (size_t)(b * 8 + m) * 131072;
  for (int i = tid; i < 144 * 32; i += 256) {
    int pos = i >> 5, dd = i & 31;
    int hh = h0 + (pos / 12) - 2, ww = w0 + (pos % 12) - 2;
    float val = 0.f;
    if (hh >= 0 && hh < 64 && ww >= 0 && ww < 64) {
      int r2 = ((hh >> 3) << 3) | (ww >> 3), s2 = ((hh & 7) << 3) | (ww & 7);
      val = (float)v[bm + r2 * 2048 + s2 * 32 + dd];
    }
    Ls[pos][dd] = val;
  }
  for (int i = tid; i < 800; i += 256) {
    int tap = i >> 5, dd = i & 31;
    Ws[tap][dd] = lw[(m * 32 + dd) * 25 + tap];
  }
  __syncthreads();
  int c = m * 32 + d;
  float bias = lb[c];
  for (int j = 0; j < 8; j++) {
    int p = (tid >> 5) + (j << 3);
    int ph = p >> 3, pww = p & 7;
    float acc = bias;
#pragma unroll
    for (int dh = 0; dh < 5; dh++)
#pragma unroll
      for (int dw = 0; dw < 5; dw++)
        acc += Ls[(ph + dh) * 12 + (pww + dw)][d] * Ws[dh * 5 + dw][d];
    acc += ao[bm + r * 2048 + p * 32 + d];
    tout[((size_t)(b * 4096 + (h0 + ph) * 64 + (w0 + pww))) * 256 + c] =
        (__bf16)acc;
  }
}

extern "C" void kernel_launch(void* const* d_in, const int* in_sizes, int n_in,
                              void* d_out, int out_size, void* d_ws, size_t ws_size,
                              hipStream_t stream) {
  (void)in_sizes; (void)n_in; (void)out_size; (void)ws_size;
  const float* x      = (const float*)d_in[0];
  const float* pos_w  = (const float*)d_in[1];
  const float* pos_b  = (const float*)d_in[2];
  const float* ln1_g  = (const float*)d_in[3];
  const float* ln1_b  = (const float*)d_in[4];
  const float* qkv_w  = (const float*)d_in[5];
  const float* qkv_b  = (const float*)d_in[6];
  const float* lepe_w = (const float*)d_in[7];
  const float* lepe_b = (const float*)d_in[8];
  const float* out_w  = (const float*)d_in[9];
  const float* out_b  = (const float*)d_in[10];
  const float* ln2_g  = (const float*)d_in[11];
  const float* ln2_b  = (const float*)d_in[12];
  const float* mlp_w1 = (const float*)d_in[13];
  const float* mlp_b1 = (const float*)d_in[14];
  const float* mlp_w2 = (const float*)d_in[15];
  const float* mlp_b2 = (const float*)d_in[16];

  float* ws = (float*)d_ws;
  const size_t P = 8ull * 4096 * 256;  // 8.39M floats
  size_t off = 0;
  float* xa = ws + off; off += P;        // residual stream NHWC fp32
  float* q  = ws + off; off += P;        // q fp32 seq; also xt scratch
  __bf16* k = (__bf16*)(ws + off); off += P / 2;   // k bf16 seq
  __bf16* v = (__bf16*)(ws + off); off += P / 2;   // v bf16 seq
  __bf16* lnb = (__bf16*)(ws + off); off += P / 2; // bf16 activations
  __bf16* hb  = (__bf16*)(ws + off); off += 12582912; // MLP hidden [32768][768] bf16
  __bf16* wq  = (__bf16*)(ws + off); off += 98304;   // [768][256]
  __bf16* wo  = (__bf16*)(ws + off); off += 32768;   // [256][256]
  __bf16* w1t = (__bf16*)(ws + off); off += 98304;   // [768][256]
  __bf16* w2t = (__bf16*)(ws + off); off += 98304;   // [256][768]
  float* qr  = ws + off; off += 131072;
  float* kr  = ws + off; off += 131072;
  float* lnm = ws + off; off += 131072;
  int* ridx  = (int*)(ws + off);

  // 0) weight prep
  wprep_kernel<<<768, 256, 0, stream>>>(qkv_w, out_w, mlp_w1, mlp_w2,
                                        wq, wo, w1t, w2t);
  // 1) NCHW -> NHWC transpose of x into q (scratch)
  transpose_kernel<<<dim3(64, 4, 8), 256, 0, stream>>>(x, q, 256, 4096);
  // 2) pos dwconv + residual, NHWC
  posconv_kernel<<<2048, 256, 0, stream>>>(q, pos_w, pos_b, xa);
  // 3) LN1 -> bf16
  ln_kernel<<<32768, 64, 0, stream>>>(xa, ln1_g, ln1_b, lnb);
  // 4) routing path, fp32-exact
  lnmean_kernel<<<512, 256, 0, stream>>>(xa, ln1_g, ln1_b, lnm);
  qkr_kernel<<<512, 256, 0, stream>>>(lnm, qkv_w, qkv_b, qr, kr);
  routing_kernel<<<8, 256, 0, stream>>>(qr, kr, ridx);
  // 5) qkv GEMM (MFMA bf16): q fp32, k/v bf16 seq layout
  mfma_gemm<0><<<dim3(6, 256), 256, 0, stream>>>(
      lnb, wq, qkv_b, nullptr, nullptr, nullptr, q, k, v, 768, 256, 0);
  // 6) sparse attention (writes into q)
  attn_kernel<<<4096, 256, 0, stream>>>(q, k, v, ridx);
  // 7) seq2grid + LEPE dwconv5x5 -> lnb (bf16 t)
  lepe_kernel<<<4096, 256, 0, stream>>>(q, v, lepe_w, lepe_b, lnb);
  // 8) out projection + residual into xa
  mfma_gemm<1><<<dim3(2, 256), 256, 0, stream>>>(
      lnb, wo, out_b, xa, xa, nullptr, nullptr, nullptr, nullptr, 256, 256, 0);
  // 9) LN2 -> bf16
  ln_kernel<<<32768, 64, 0, stream>>>(xa, ln2_g, ln2_b, lnb);
  // 10) MLP single pass; mlp2 writes d_out NCHW directly (fused transpose)
  mfma_gemm<2><<<dim3(6, 256), 256, 0, stream>>>(
      lnb, w1t, mlp_b1, nullptr, nullptr, hb, nullptr, nullptr, nullptr,
      768, 256, 0);
  mfma_gemm<3><<<dim3(2, 256), 256, 0, stream>>>(
      hb, w2t, mlp_b2, xa, (float*)d_out, nullptr, nullptr, nullptr, nullptr,
      256, 768, 0);
}

// Round 10
// 834.731 us; speedup vs baseline: 1.1193x; 1.1193x over previous
//
#include <hip/hip_runtime.h>
#include <cmath>

// Problem constants
// B=8, C=256, H=W=64, HW=4096, NT=32768 tokens
// heads M=8, head dim D=32, regions NR=64 (8x8 of 8x8), RSQ=64, TOPK=4, KSEL=32

typedef __bf16 bf16x8 __attribute__((ext_vector_type(8)));
typedef __bf16 bf16x4 __attribute__((ext_vector_type(4)));
typedef float f32x4 __attribute__((ext_vector_type(4)));
typedef float f32x2 __attribute__((ext_vector_type(2)));

__device__ __forceinline__ void async_copy16(const __bf16* g, __bf16* l) {
  __builtin_amdgcn_global_load_lds(
      (const __attribute__((address_space(1))) void*)g,
      (__attribute__((address_space(3))) void*)l, 16, 0, 0);
}

// ---------------------------------------------------------------------------
// Tiled transpose: per batch, src [R][Cc] -> dst [Cc][R]. 64x64 tiles.
// (input NCHW->NHWC only; output written NCHW by mlp2 epilogue)
// ---------------------------------------------------------------------------
__global__ __launch_bounds__(256) void transpose_kernel(
    const float* __restrict__ src, float* __restrict__ dst, int R, int Cc) {
  __shared__ float T[64][65];
  int b = blockIdx.z;
  int r0 = blockIdx.y * 64, c0 = blockIdx.x * 64;
  const float* S = src + (size_t)b * R * Cc;
  float* D = dst + (size_t)b * R * Cc;
  int lane = threadIdx.x & 63, wq = threadIdx.x >> 6;
#pragma unroll
  for (int j = 0; j < 16; j++) {
    int rr = wq + j * 4;
    T[rr][lane] = S[(size_t)(r0 + rr) * Cc + c0 + lane];
  }
  __syncthreads();
#pragma unroll
  for (int j = 0; j < 16; j++) {
    int cc = wq + j * 4;
    D[(size_t)(c0 + cc) * R + r0 + lane] = T[lane][cc];
  }
}

// ---------------------------------------------------------------------------
// FUSED K1: per (b, region): xa = xt + dwconv3x3(xt,pos)  [fp32, NHWC]
//           lnb = LN1(xa) -> bf16 ; lnm = region-mean of LN1 (routing input)
// Replaces posconv + ln_kernel(LN1) + lnmean: saves 2 full xa read passes.
// LDS: Halo 100x256 fp32 (102.4KB, reused as Out[64][256]) + Wl 9x256
// (9.2KB, reused as LN partials). 1 block/CU.
// ---------------------------------------------------------------------------
__global__ __launch_bounds__(256) void posln_kernel(
    const float* __restrict__ xt, const float* __restrict__ pw,
    const float* __restrict__ pb, const float* __restrict__ g1,
    const float* __restrict__ b1, float* __restrict__ xa,
    __bf16* __restrict__ lnb, float* __restrict__ lnm) {
  __shared__ float Halo[25600];  // [pos 0..99][ch 0..255]; reused as Out[64][256]
  __shared__ float Wl[2304];     // [tap 0..8][ch]; reused as partial[4][256]
  int blk = blockIdx.x;          // 8*64
  int b = blk >> 6, r = blk & 63;
  int h0 = (r >> 3) << 3, w0 = (r & 7) << 3;
  int tid = threadIdx.x;
  const float* src = xt + (size_t)b * 4096 * 256;
  for (int i = tid; i < 25600; i += 256) {
    int pos = i >> 8, c = i & 255;
    int hh = h0 + pos / 10 - 1, ww = w0 + (pos % 10) - 1;
    float val = 0.f;
    if (hh >= 0 && hh < 64 && ww >= 0 && ww < 64)
      val = src[(size_t)(hh * 64 + ww) * 256 + c];
    Halo[i] = val;
  }
  for (int i = tid; i < 2304; i += 256) {
    int tap = i >> 8, c = i & 255;
    Wl[i] = pw[c * 9 + tap];
  }
  __syncthreads();
  // conv phase: thread = channel, 64 tokens each, outputs kept in registers
  int c = tid;
  float bias = pb[c];
  float o64[64];
#pragma unroll
  for (int p = 0; p < 64; p++) {
    int ph = p >> 3, pww = p & 7;
    float acc = bias;
#pragma unroll
    for (int dh = 0; dh < 3; dh++)
#pragma unroll
      for (int dw = 0; dw < 3; dw++)
        acc += Halo[((ph + dh) * 10 + (pww + dw)) * 256 + c] *
               Wl[(dh * 3 + dw) * 256 + c];
    float o = Halo[((ph + 1) * 10 + (pww + 1)) * 256 + c] + acc;
    o64[p] = o;
    xa[((size_t)(b * 4096 + (h0 + ph) * 64 + (w0 + pww))) * 256 + c] = o;
  }
  __syncthreads();
#pragma unroll
  for (int p = 0; p < 64; p++) Halo[p * 256 + c] = o64[p];
  __syncthreads();
  // LN phase: wave w handles tokens w*16..w*16+15, 64 lanes x 4 channel-chunks
  int wave = tid >> 6, lane = tid & 63;
  float ga = g1[lane], gb = g1[lane + 64], gc = g1[lane + 128], gd = g1[lane + 192];
  float ba = b1[lane], bbb = b1[lane + 64], bc = b1[lane + 128], bd = b1[lane + 192];
  float a0 = 0.f, a1 = 0.f, a2 = 0.f, a3 = 0.f;
  for (int t = 0; t < 16; t++) {
    int p = wave * 16 + t;
    const float* row = &Halo[p * 256];
    float v0 = row[lane], v1 = row[lane + 64], v2 = row[lane + 128], v3 = row[lane + 192];
    float s = v0 + v1 + v2 + v3;
#pragma unroll
    for (int off = 32; off; off >>= 1) s += __shfl_xor(s, off);
    float mu = s * (1.f / 256.f);
    float d0 = v0 - mu, d1 = v1 - mu, d2 = v2 - mu, d3 = v3 - mu;
    float sq = d0 * d0 + d1 * d1 + d2 * d2 + d3 * d3;
#pragma unroll
    for (int off = 32; off; off >>= 1) sq += __shfl_xor(sq, off);
    float rstd = rsqrtf(sq * (1.f / 256.f) + 1e-6f);
    float n0 = d0 * rstd, n1 = d1 * rstd, n2 = d2 * rstd, n3 = d3 * rstd;
    int h = h0 + (p >> 3), w = w0 + (p & 7);
    __bf16* o = lnb + ((size_t)(b * 4096 + h * 64 + w)) * 256;
    o[lane]       = (__bf16)(n0 * ga + ba);
    o[lane + 64]  = (__bf16)(n1 * gb + bbb);
    o[lane + 128] = (__bf16)(n2 * gc + bc);
    o[lane + 192] = (__bf16)(n3 * gd + bd);
    a0 += n0; a1 += n1; a2 += n2; a3 += n3;
  }
  Wl[wave * 256 + lane] = a0;
  Wl[wave * 256 + lane + 64] = a1;
  Wl[wave * 256 + lane + 128] = a2;
  Wl[wave * 256 + lane + 192] = a3;
  __syncthreads();
  if (wave == 0) {
    for (int ch = lane; ch < 256; ch += 64) {
      float s2 = Wl[ch] + Wl[256 + ch] + Wl[512 + ch] + Wl[768 + ch];
      lnm[(size_t)(b * 64 + r) * 256 + ch] = g1[ch] * (s2 * (1.f / 64.f)) + b1[ch];
    }
  }
}

// ---------------------------------------------------------------------------
// LayerNorm over C=256, one wave per token, bf16 output (LN2)
// ---------------------------------------------------------------------------
__global__ __launch_bounds__(64) void ln_kernel(
    const float* __restrict__ in, const float* __restrict__ g,
    const float* __restrict__ bb, __bf16* __restrict__ out) {
  int t = blockIdx.x; int l = threadIdx.x;
  const float* p = in + (size_t)t * 256;
  float v0 = p[l], v1 = p[l + 64], v2 = p[l + 128], v3 = p[l + 192];
  float s = v0 + v1 + v2 + v3;
#pragma unroll
  for (int off = 32; off; off >>= 1) s += __shfl_xor(s, off);
  float mu = s * (1.f / 256.f);
  float d0 = v0 - mu, d1 = v1 - mu, d2 = v2 - mu, d3 = v3 - mu;
  float sq = d0 * d0 + d1 * d1 + d2 * d2 + d3 * d3;
#pragma unroll
  for (int off = 32; off; off >>= 1) sq += __shfl_xor(sq, off);
  float rstd = rsqrtf(sq * (1.f / 256.f) + 1e-6f);
  __bf16* o = out + (size_t)t * 256;
  o[l]       = (__bf16)(d0 * rstd * g[l]       + bb[l]);
  o[l + 64]  = (__bf16)(d1 * rstd * g[l + 64]  + bb[l + 64]);
  o[l + 128] = (__bf16)(d2 * rstd * g[l + 128] + bb[l + 128]);
  o[l + 192] = (__bf16)(d3 * rstd * g[l + 192] + bb[l + 192]);
}

// ---------------------------------------------------------------------------
// Weight prep: bf16-convert qkv_w [768][256], out_w [256][256] (already [N][K]),
// transpose+convert mlp_w1 [256][768]->[768][256], mlp_w2 [768][256]->[256][768]
// ---------------------------------------------------------------------------
__global__ __launch_bounds__(256) void wprep_kernel(
    const float* __restrict__ qkv_w, const float* __restrict__ out_w,
    const float* __restrict__ w1, const float* __restrict__ w2,
    __bf16* __restrict__ wq, __bf16* __restrict__ wo,
    __bf16* __restrict__ w1t, __bf16* __restrict__ w2t) {
  int i = blockIdx.x * 256 + threadIdx.x;
  if (i < 196608) wq[i] = (__bf16)qkv_w[i];
  if (i < 65536) wo[i] = (__bf16)out_w[i];
  if (i < 196608) {  // w1t[n][k] = w1[k][n], n<768, k<256
    int n = i >> 8, k2 = i & 255;
    w1t[i] = (__bf16)w1[k2 * 768 + n];
  }
  if (i < 196608) {  // w2t[n][k] = w2[k][n], n<256, k<768
    int n = i / 768, k2 = i % 768;
    w2t[i] = (__bf16)w2[k2 * 256 + n];
  }
}

// ---------------------------------------------------------------------------
// MFMA bf16 GEMM: C[row][col] = epi( sum_k A[row][k]*Bw[col][k] + bias[col] )
// A [M][K] bf16, Bw [N][K] bf16. 128x128 tile, BK=32, 4 waves (2x2 quadrants),
// global_load_lds width-16 staging, mfma_f32_16x16x32_bf16.
// EPI: 0 = scatter to q(fp32)/k,v(bf16) seq layout; 1 = fp32 res+val;
//      2 = gelu -> bf16; 3 = res+val written NCHW fp32 (fused transpose)
// ---------------------------------------------------------------------------
template <int EPI>
__global__ __launch_bounds__(256) void mfma_gemm(
    const __bf16* __restrict__ A, const __bf16* __restrict__ Bw,
    const float* __restrict__ bias, const float* __restrict__ res,
    float* __restrict__ out, __bf16* __restrict__ outb,
    float* __restrict__ qd, __bf16* __restrict__ kd, __bf16* __restrict__ vd,
    int N, int K, int row0) {
  __shared__ __bf16 Asl[128 * 32];
  __shared__ __bf16 Bsl[128 * 32];
  int tid = threadIdx.x;
  int lane = tid & 63, wave = tid >> 6;
  int m0 = blockIdx.y * 128, n0 = blockIdx.x * 128;
  int wr = (wave >> 1) * 64, wc = (wave & 1) * 64;

  f32x4 acc[4][4];
  f32x4 z = {0.f, 0.f, 0.f, 0.f};
#pragma unroll
  for (int i = 0; i < 4; i++)
#pragma unroll
    for (int j = 0; j < 4; j++) acc[i][j] = z;

  int srow = (lane >> 2);          // 0..15
  int skoff = (lane & 3) * 8;      // 0,8,16,24
  for (int k0 = 0; k0 < K; k0 += 32) {
#pragma unroll
    for (int j = 0; j < 2; j++) {
      int rbase = wave * 32 + j * 16;
      const __bf16* ga = A + (size_t)(m0 + rbase + srow) * K + k0 + skoff;
      const __bf16* gb = Bw + (size_t)(n0 + rbase + srow) * K + k0 + skoff;
      async_copy16(ga, &Asl[rbase * 32]);
      async_copy16(gb, &Bsl[rbase * 32]);
    }
    __syncthreads();
    bf16x8 af[4], bf[4];
#pragma unroll
    for (int t = 0; t < 4; t++) {
      af[t] = *(const bf16x8*)&Asl[(wr + t * 16 + (lane & 15)) * 32 + (lane >> 4) * 8];
      bf[t] = *(const bf16x8*)&Bsl[(wc + t * 16 + (lane & 15)) * 32 + (lane >> 4) * 8];
    }
#pragma unroll
    for (int ti = 0; ti < 4; ti++)
#pragma unroll
      for (int tj = 0; tj < 4; tj++)
        acc[ti][tj] = __builtin_amdgcn_mfma_f32_16x16x32_bf16(
            af[ti], bf[tj], acc[ti][tj], 0, 0, 0);
    __syncthreads();
  }
  // epilogue: C/D layout col=lane&15, row=(lane>>4)*4+reg
#pragma unroll
  for (int ti = 0; ti < 4; ti++) {
#pragma unroll
    for (int tj = 0; tj < 4; tj++) {
      int colg = n0 + wc + tj * 16 + (lane & 15);
      float bv = bias[colg];
#pragma unroll
      for (int reg = 0; reg < 4; reg++) {
        int rowg = m0 + wr + ti * 16 + (lane >> 4) * 4 + reg;
        float val = acc[ti][tj][reg] + bv;
        if (EPI == 0) {
          int tns = colg >> 8, cc = colg & 255, m = cc >> 5, d = cc & 31;
          int grow = row0 + rowg;
          int b = grow >> 12, hw = grow & 4095, h = hw >> 6, w = hw & 63;
          int r = ((h >> 3) << 3) | (w >> 3), s2 = ((h & 7) << 3) | (w & 7);
          size_t addr = (size_t)(b * 8 + m) * 131072 + r * 2048 + s2 * 32 + d;
          if (tns == 0) qd[addr] = val;
          else if (tns == 1) kd[addr] = (__bf16)val;
          else vd[addr] = (__bf16)val;
        } else if (EPI == 1) {
          out[(size_t)rowg * N + colg] = res[(size_t)rowg * N + colg] + val;
        } else if (EPI == 2) {
          outb[(size_t)rowg * N + colg] =
              (__bf16)(0.5f * val * (1.f + erff(val * 0.70710678118654752f)));
        } else {
          int grow = row0 + rowg;
          int b = grow >> 12, hw = grow & 4095;
          out[(size_t)(b * 256 + colg) * 4096 + hw] =
              res[(size_t)grow * 256 + colg] + val;
        }
      }
    }
  }
}

__global__ __launch_bounds__(256) void qkr_kernel(
    const float* __restrict__ lnm, const float* __restrict__ qkv_w,
    const float* __restrict__ qkv_b, float* __restrict__ qr,
    float* __restrict__ kr) {
  __shared__ float xm[256];
  int br = blockIdx.x, c = threadIdx.x;
  xm[c] = lnm[(size_t)br * 256 + c];
  __syncthreads();
  const float* wqp = qkv_w + (size_t)c * 256;
  const float* wkp = qkv_w + (size_t)(256 + c) * 256;
  float aq = 0.f, ak = 0.f;
  for (int k2 = 0; k2 < 256; k2++) {
    float xv = xm[k2];
    aq += wqp[k2] * xv; ak += wkp[k2] * xv;
  }
  qr[(size_t)br * 256 + c] = aq + qkv_b[c];
  kr[(size_t)br * 256 + c] = ak + qkv_b[256 + c];
}

// ---------------------------------------------------------------------------
// R2: a_r = q_r @ k_r^T per batch; top-4 regions per row (jax tie: lower idx)
// ---------------------------------------------------------------------------
__global__ __launch_bounds__(256) void routing_kernel(
    const float* __restrict__ qr, const float* __restrict__ kr,
    int* __restrict__ idxout) {
  __shared__ float Ar[64 * 64];
  int b = blockIdx.x; int tid = threadIdx.x;
  int i = tid >> 2, jg = tid & 3;
  const float* qrow = qr + (size_t)(b * 64 + i) * 256;
  for (int jj = 0; jj < 16; jj++) {
    int j = jg * 16 + jj;
    const float* krow = kr + (size_t)(b * 64 + j) * 256;
    float acc = 0.f;
    for (int c = 0; c < 256; c++) acc += qrow[c] * krow[c];
    Ar[i * 64 + j] = acc;
  }
  __syncthreads();
  if (tid < 64) {
    float v0 = -INFINITY, v1 = -INFINITY, v2 = -INFINITY, v3 = -INFINITY;
    int i0 = 0, i1 = 0, i2 = 0, i3 = 0;
    for (int j = 0; j < 64; j++) {
      float s = Ar[tid * 64 + j];
      if (s > v0)      { v3=v2;i3=i2; v2=v1;i2=i1; v1=v0;i1=i0; v0=s;i0=j; }
      else if (s > v1) { v3=v2;i3=i2; v2=v1;i2=i1; v1=s;i1=j; }
      else if (s > v2) { v3=v2;i3=i2; v2=s;i2=j; }
      else if (s > v3) { v3=s;i3=j; }
    }
    int* op = idxout + (b * 64 + tid) * 4;
    op[0] = i0; op[1] = i1; op[2] = i2; op[3] = i3;
  }
}

// ---------------------------------------------------------------------------
// Attention per (b,m,r): r8's proven config — 16-bit ballot radix-select,
// packed f32x2 scores, launch_bounds(256,2) = 124 VGPR, NO spill.
// (r9's (256,4) made the allocator jump to 64 VGPRs and spill: FETCH 69->717MB,
// 267->399us. Frozen at (256,2).)
// ---------------------------------------------------------------------------
__global__ __launch_bounds__(256, 2) void attn_kernel(
    float* __restrict__ qio, const __bf16* __restrict__ kbuf,
    const __bf16* __restrict__ vbuf, const int* __restrict__ idx) {
  __shared__ __bf16 Ks[256 * 32];
  __shared__ __bf16 Vs[256 * 32];
  __shared__ float wbuf[4][4][32];
  __shared__ unsigned short cbuf[4][4][32];
  int blk = blockIdx.x; int r = blk & 63; int m = (blk >> 6) & 7; int b = blk >> 9;
  int tid = threadIdx.x;
  int lane = tid & 63, wave = tid >> 6;
  const int* ip = idx + (b * 64 + r) * 4;
  int rg0 = ip[0], rg1 = ip[1], rg2 = ip[2], rg3 = ip[3];
  size_t bm = (size_t)(b * 8 + m) * 131072;

  {
    int rgs[4] = {rg0, rg1, rg2, rg3};
    int s = tid >> 2, g8 = tid & 3;
#pragma unroll
    for (int t = 0; t < 4; t++) {
      const uint4* sk = (const uint4*)(kbuf + bm + rgs[t] * 2048);
      const uint4* sv = (const uint4*)(vbuf + bm + rgs[t] * 2048);
      int kk = (t << 6) | s;
      uint4 kw = sk[tid];
      uint4 vw = sv[tid];
      int dg0 = g8 * 2, dg1 = dg0 + 1;
      uint2 lo; lo.x = kw.x; lo.y = kw.y;
      uint2 hi; hi.x = kw.z; hi.y = kw.w;
      *(uint2*)&Ks[(kk << 5) + (((dg0 + (kk >> 1)) & 7) << 2)] = lo;
      *(uint2*)&Ks[(kk << 5) + (((dg1 + (kk >> 1)) & 7) << 2)] = hi;
      *(uint4*)&Vs[(kk << 5) + (g8 << 3)] = vw;
    }
  }
  __syncthreads();

  const float* qb = qio + bm + r * 2048;
  const float scale = 1.f / 16.f;  // C^-0.5

  for (int g = 0; g < 4; g++) {
    int row0 = (wave << 4) | (g << 2);
    f32x2 sc2[4][4];
    f32x2 z2 = {0.f, 0.f};
#pragma unroll
    for (int i = 0; i < 4; i++)
#pragma unroll
      for (int t = 0; t < 4; t++) sc2[i][t] = z2;
    const f32x2* qp0 = (const f32x2*)(qb + (row0 + 0) * 32);
    const f32x2* qp1 = (const f32x2*)(qb + (row0 + 1) * 32);
    const f32x2* qp2 = (const f32x2*)(qb + (row0 + 2) * 32);
    const f32x2* qp3 = (const f32x2*)(qb + (row0 + 3) * 32);
#pragma unroll
    for (int dg = 0; dg < 8; dg++) {
      f32x2 q0a = qp0[dg * 2], q0b = qp0[dg * 2 + 1];
      f32x2 q1a = qp1[dg * 2], q1b = qp1[dg * 2 + 1];
      f32x2 q2a = qp2[dg * 2], q2b = qp2[dg * 2 + 1];
      f32x2 q3a = qp3[dg * 2], q3b = qp3[dg * 2 + 1];
#pragma unroll
      for (int t = 0; t < 4; t++) {
        int kk = (t << 6) | lane;
        const unsigned* kp =
            (const unsigned*)&Ks[(kk << 5) | (((dg + (kk >> 1)) & 7) << 2)];
        unsigned lo = kp[0], hi = kp[1];
        f32x2 kxy, kzw;
        kxy.x = __uint_as_float(lo << 16);
        kxy.y = __uint_as_float(lo & 0xffff0000u);
        kzw.x = __uint_as_float(hi << 16);
        kzw.y = __uint_as_float(hi & 0xffff0000u);
        sc2[0][t] = sc2[0][t] + q0a * kxy + q0b * kzw;
        sc2[1][t] = sc2[1][t] + q1a * kxy + q1b * kzw;
        sc2[2][t] = sc2[2][t] + q2a * kxy + q2b * kzw;
        sc2[3][t] = sc2[3][t] + q3a * kxy + q3b * kzw;
      }
    }
    // horizontal add + scale, then 16-bit monotone key
    float sc[4][4];
    unsigned uk[4][4];
#pragma unroll
    for (int i = 0; i < 4; i++)
#pragma unroll
      for (int t = 0; t < 4; t++) {
        float v = (sc2[i][t].x + sc2[i][t].y) * scale;
        sc[i][t] = v;
        unsigned bu = __float_as_uint(v);
        uk[i][t] = (bu ^ (unsigned)(((int)bu >> 31) | 0x80000000)) >> 16;
      }
    unsigned p0 = 0, p1 = 0, p2 = 0, p3 = 0;
    for (int bit = 15; bit >= 0; --bit) {
      unsigned msk = 1u << bit;
      unsigned c0 = p0 | msk, c1 = p1 | msk, c2 = p2 | msk, c3 = p3 | msk;
      int n0 = __popcll(__ballot(uk[0][0] >= c0)) + __popcll(__ballot(uk[0][1] >= c0)) +
               __popcll(__ballot(uk[0][2] >= c0)) + __popcll(__ballot(uk[0][3] >= c0));
      int n1 = __popcll(__ballot(uk[1][0] >= c1)) + __popcll(__ballot(uk[1][1] >= c1)) +
               __popcll(__ballot(uk[1][2] >= c1)) + __popcll(__ballot(uk[1][3] >= c1));
      int n2 = __popcll(__ballot(uk[2][0] >= c2)) + __popcll(__ballot(uk[2][1] >= c2)) +
               __popcll(__ballot(uk[2][2] >= c2)) + __popcll(__ballot(uk[2][3] >= c2));
      int n3 = __popcll(__ballot(uk[3][0] >= c3)) + __popcll(__ballot(uk[3][1] >= c3)) +
               __popcll(__ballot(uk[3][2] >= c3)) + __popcll(__ballot(uk[3][3] >= c3));
      if (n0 >= 32) p0 = c0;
      if (n1 >= 32) p1 = c1;
      if (n2 >= 32) p2 = c2;
      if (n3 >= 32) p3 = c3;
    }
    unsigned pr[4] = {p0, p1, p2, p3};
#pragma unroll
    for (int i = 0; i < 4; i++) {
      unsigned T = pr[i];
      unsigned ub = T << 16;  // lower bound of the 16-bit tie class
      unsigned tb = (ub & 0x80000000u) ? (ub ^ 0x80000000u) : ~ub;
      float Tv = __uint_as_float(tb);
      unsigned long long gb[4], eb[4];
#pragma unroll
      for (int t = 0; t < 4; t++) {
        gb[t] = __ballot(uk[i][t] > T);
        eb[t] = __ballot(uk[i][t] == T);
      }
      int bg1 = __popcll(gb[0]), bg2 = bg1 + __popcll(gb[1]), bg3 = bg2 + __popcll(gb[2]);
      int cgt = bg3 + __popcll(gb[3]);
      int be1 = __popcll(eb[0]), be2 = be1 + __popcll(eb[1]), be3 = be2 + __popcll(eb[2]);
      int need = 32 - cgt;
      int bgs[4] = {0, bg1, bg2, bg3};
      int bes[4] = {0, be1, be2, be3};
#pragma unroll
      for (int t = 0; t < 4; t++) {
        int rgt = bgs[t] + __builtin_amdgcn_mbcnt_hi(
                               (unsigned)(gb[t] >> 32),
                               __builtin_amdgcn_mbcnt_lo((unsigned)gb[t], 0));
        int ret = bes[t] + __builtin_amdgcn_mbcnt_hi(
                               (unsigned)(eb[t] >> 32),
                               __builtin_amdgcn_mbcnt_lo((unsigned)eb[t], 0));
        bool isg = uk[i][t] > T;
        bool sel = isg || (uk[i][t] == T && ret < need);
        int slot = isg ? rgt : (cgt + ret);
        if (sel) {
          wbuf[wave][i][slot] = __expf(sc[i][t] - Tv);
          cbuf[wave][i][slot] = (unsigned short)((t << 6) | lane);
        }
      }
    }
#pragma unroll
    for (int i = 0; i < 4; i++) {
      int dd = lane & 31, half = lane >> 5;
      float acc = 0.f, wsum = 0.f;
#pragma unroll
      for (int it2 = 0; it2 < 16; it2++) {
        int sl = (half << 4) | it2;
        float wi = wbuf[wave][i][sl];
        int ci = cbuf[wave][i][sl];
        acc += wi * (float)Vs[(ci << 5) | dd];
        wsum += wi;
      }
      acc += __shfl_xor(acc, 32);
      wsum += __shfl_xor(wsum, 32);
      if (lane < 32) qio[bm + r * 2048 + (row0 + i) * 32 + dd] = acc / wsum;
    }
  }
}

// ---------------------------------------------------------------------------
// K6: t = seq2grid(attn_out) + dwconv5x5(v) + lepe_b, NHWC bf16 out.
// ---------------------------------------------------------------------------
__global__ __launch_bounds__(256) void lepe_kernel(
    const float* __restrict__ ao, const __bf16* __restrict__ v,
    const float* __restrict__ lw, const float* __restrict__ lb,
    __bf16* __restrict__ tout) {
  __shared__ float Ls[144][32];
  __shared__ float Ws[25][32];
  int blk = blockIdx.x;  // 8*8*64
  int b = blk >> 9, m = (blk >> 6) & 7, r = blk & 63;
  int h0 = (r >> 3) << 3, w0 = (r & 7) << 3;
  int tid = threadIdx.x, d = tid & 31;
  size_t bm = (size_t)(b * 8 + m) * 131072;
  for (int i = tid; i < 144 * 32; i += 256) {
    int pos = i >> 5, dd = i & 31;
    int hh = h0 + (pos / 12) - 2, ww = w0 + (pos % 12) - 2;
    float val = 0.f;
    if (hh >= 0 && hh < 64 && ww >= 0 && ww < 64) {
      int r2 = ((hh >> 3) << 3) | (ww >> 3), s2 = ((hh & 7) << 3) | (ww & 7);
      val = (float)v[bm + r2 * 2048 + s2 * 32 + dd];
    }
    Ls[pos][dd] = val;
  }
  for (int i = tid; i < 800; i += 256) {
    int tap = i >> 5, dd = i & 31;
    Ws[tap][dd] = lw[(m * 32 + dd) * 25 + tap];
  }
  __syncthreads();
  int c = m * 32 + d;
  float bias = lb[c];
  for (int j = 0; j < 8; j++) {
    int p = (tid >> 5) + (j << 3);
    int ph = p >> 3, pww = p & 7;
    float acc = bias;
#pragma unroll
    for (int dh = 0; dh < 5; dh++)
#pragma unroll
      for (int dw = 0; dw < 5; dw++)
        acc += Ls[(ph + dh) * 12 + (pww + dw)][d] * Ws[dh * 5 + dw][d];
    acc += ao[bm + r * 2048 + p * 32 + d];
    tout[((size_t)(b * 4096 + (h0 + ph) * 64 + (w0 + pww))) * 256 + c] =
        (__bf16)acc;
  }
}

extern "C" void kernel_launch(void* const* d_in, const int* in_sizes, int n_in,
                              void* d_out, int out_size, void* d_ws, size_t ws_size,
                              hipStream_t stream) {
  (void)in_sizes; (void)n_in; (void)out_size; (void)ws_size;
  const float* x      = (const float*)d_in[0];
  const float* pos_w  = (const float*)d_in[1];
  const float* pos_b  = (const float*)d_in[2];
  const float* ln1_g  = (const float*)d_in[3];
  const float* ln1_b  = (const float*)d_in[4];
  const float* qkv_w  = (const float*)d_in[5];
  const float* qkv_b  = (const float*)d_in[6];
  const float* lepe_w = (const float*)d_in[7];
  const float* lepe_b = (const float*)d_in[8];
  const float* out_w  = (const float*)d_in[9];
  const float* out_b  = (const float*)d_in[10];
  const float* ln2_g  = (const float*)d_in[11];
  const float* ln2_b  = (const float*)d_in[12];
  const float* mlp_w1 = (const float*)d_in[13];
  const float* mlp_b1 = (const float*)d_in[14];
  const float* mlp_w2 = (const float*)d_in[15];
  const float* mlp_b2 = (const float*)d_in[16];

  float* ws = (float*)d_ws;
  const size_t P = 8ull * 4096 * 256;  // 8.39M floats
  size_t off = 0;
  float* xa = ws + off; off += P;        // residual stream NHWC fp32
  float* q  = ws + off; off += P;        // q fp32 seq; also xt scratch
  __bf16* k = (__bf16*)(ws + off); off += P / 2;   // k bf16 seq
  __bf16* v = (__bf16*)(ws + off); off += P / 2;   // v bf16 seq
  __bf16* lnb = (__bf16*)(ws + off); off += P / 2; // bf16 activations
  __bf16* hb  = (__bf16*)(ws + off); off += 12582912; // MLP hidden [32768][768] bf16
  __bf16* wq  = (__bf16*)(ws + off); off += 98304;   // [768][256]
  __bf16* wo  = (__bf16*)(ws + off); off += 32768;   // [256][256]
  __bf16* w1t = (__bf16*)(ws + off); off += 98304;   // [768][256]
  __bf16* w2t = (__bf16*)(ws + off); off += 98304;   // [256][768]
  float* qr  = ws + off; off += 131072;
  float* kr  = ws + off; off += 131072;
  float* lnm = ws + off; off += 131072;
  int* ridx  = (int*)(ws + off);

  // 0) weight prep
  wprep_kernel<<<768, 256, 0, stream>>>(qkv_w, out_w, mlp_w1, mlp_w2,
                                        wq, wo, w1t, w2t);
  // 1) NCHW -> NHWC transpose of x into q (scratch)
  transpose_kernel<<<dim3(64, 4, 8), 256, 0, stream>>>(x, q, 256, 4096);
  // 2) FUSED pos dwconv + residual + LN1 + region-mean
  posln_kernel<<<512, 256, 0, stream>>>(q, pos_w, pos_b, ln1_g, ln1_b,
                                        xa, lnb, lnm);
  // 3) routing path, fp32-exact
  qkr_kernel<<<512, 256, 0, stream>>>(lnm, qkv_w, qkv_b, qr, kr);
  routing_kernel<<<8, 256, 0, stream>>>(qr, kr, ridx);
  // 4) qkv GEMM (MFMA bf16): q fp32, k/v bf16 seq layout
  mfma_gemm<0><<<dim3(6, 256), 256, 0, stream>>>(
      lnb, wq, qkv_b, nullptr, nullptr, nullptr, q, k, v, 768, 256, 0);
  // 5) sparse attention (writes into q)
  attn_kernel<<<4096, 256, 0, stream>>>(q, k, v, ridx);
  // 6) seq2grid + LEPE dwconv5x5 -> lnb (bf16 t)
  lepe_kernel<<<4096, 256, 0, stream>>>(q, v, lepe_w, lepe_b, lnb);
  // 7) out projection + residual into xa
  mfma_gemm<1><<<dim3(2, 256), 256, 0, stream>>>(
      lnb, wo, out_b, xa, xa, nullptr, nullptr, nullptr, nullptr, 256, 256, 0);
  // 8) LN2 -> bf16
  ln_kernel<<<32768, 64, 0, stream>>>(xa, ln2_g, ln2_b, lnb);
  // 9) MLP single pass; mlp2 writes d_out NCHW directly (fused transpose)
  mfma_gemm<2><<<dim3(6, 256), 256, 0, stream>>>(
      lnb, w1t, mlp_b1, nullptr, nullptr, hb, nullptr, nullptr, nullptr,
      768, 256, 0);
  mfma_gemm<3><<<dim3(2, 256), 256, 0, stream>>>(
      hb, w2t, mlp_b2, xa, (float*)d_out, nullptr, nullptr, nullptr, nullptr,
      256, 768, 0);
}

// Round 11
// 785.362 us; speedup vs baseline: 1.1897x; 1.0629x over previous
//
#include <hip/hip_runtime.h>
#include <cmath>

// Problem constants
// B=8, C=256, H=W=64, HW=4096, NT=32768 tokens
// heads M=8, head dim D=32, regions NR=64 (8x8 of 8x8), RSQ=64, TOPK=4, KSEL=32

typedef __bf16 bf16x8 __attribute__((ext_vector_type(8)));
typedef __bf16 bf16x4 __attribute__((ext_vector_type(4)));
typedef float f32x4 __attribute__((ext_vector_type(4)));
typedef float f32x2 __attribute__((ext_vector_type(2)));

__device__ __forceinline__ void async_copy16(const __bf16* g, __bf16* l) {
  __builtin_amdgcn_global_load_lds(
      (const __attribute__((address_space(1))) void*)g,
      (__attribute__((address_space(3))) void*)l, 16, 0, 0);
}

// ---------------------------------------------------------------------------
// Tiled transpose: per batch, src [R][Cc] -> dst [Cc][R]. 64x64 tiles.
// (input NCHW->NHWC only; output written NCHW by mlp2 epilogue)
// ---------------------------------------------------------------------------
__global__ __launch_bounds__(256) void transpose_kernel(
    const float* __restrict__ src, float* __restrict__ dst, int R, int Cc) {
  __shared__ float T[64][65];
  int b = blockIdx.z;
  int r0 = blockIdx.y * 64, c0 = blockIdx.x * 64;
  const float* S = src + (size_t)b * R * Cc;
  float* D = dst + (size_t)b * R * Cc;
  int lane = threadIdx.x & 63, wq = threadIdx.x >> 6;
#pragma unroll
  for (int j = 0; j < 16; j++) {
    int rr = wq + j * 4;
    T[rr][lane] = S[(size_t)(r0 + rr) * Cc + c0 + lane];
  }
  __syncthreads();
#pragma unroll
  for (int j = 0; j < 16; j++) {
    int cc = wq + j * 4;
    D[(size_t)(c0 + cc) * R + r0 + lane] = T[lane][cc];
  }
}

// ---------------------------------------------------------------------------
// K1: xa = xt + dwconv3x3(xt,pos), all NHWC. (r8's proven version — the r10
// full posln fusion was 1 block/CU LDS-latency-bound and regressed.)
// ---------------------------------------------------------------------------
__global__ __launch_bounds__(256) void posconv_kernel(
    const float* __restrict__ xt, const float* __restrict__ pw,
    const float* __restrict__ pb, float* __restrict__ xa) {
  __shared__ float Ls[100][64];
  __shared__ float Ws[9][64];
  int blk = blockIdx.x;  // 8*64*4
  int b = blk >> 8, r = (blk >> 2) & 63, cg = blk & 3;
  int h0 = (r >> 3) << 3, w0 = (r & 7) << 3;
  int c0 = cg << 6;
  int tid = threadIdx.x, cl = tid & 63;
  const float* src = xt + ((size_t)b * 4096) * 256;
  for (int i = tid; i < 6400; i += 256) {
    int pos = i >> 6, ccl = i & 63;
    int hh = h0 + (pos / 10) - 1, ww = w0 + (pos % 10) - 1;
    float val = 0.f;
    if (hh >= 0 && hh < 64 && ww >= 0 && ww < 64)
      val = src[(size_t)(hh * 64 + ww) * 256 + c0 + ccl];
    Ls[pos][ccl] = val;
  }
  for (int i = tid; i < 576; i += 256) {
    int tap = i >> 6, ccl = i & 63;
    Ws[tap][ccl] = pw[(c0 + ccl) * 9 + tap];
  }
  __syncthreads();
  float bias = pb[c0 + cl];
  for (int j = 0; j < 16; j++) {
    int p = (tid >> 6) + (j << 2);
    int ph = p >> 3, pww = p & 7;
    float acc = bias;
#pragma unroll
    for (int dh = 0; dh < 3; dh++)
#pragma unroll
      for (int dw = 0; dw < 3; dw++)
        acc += Ls[(ph + dh) * 10 + (pww + dw)][cl] * Ws[dh * 3 + dw][cl];
    float xv = Ls[(ph + 1) * 10 + (pww + 1)][cl];
    xa[((size_t)(b * 4096 + (h0 + ph) * 64 + (w0 + pww))) * 256 + c0 + cl] =
        xv + acc;
  }
}

// ---------------------------------------------------------------------------
// FUSED LN1 + region-mean: block per (b, region), 4 waves x 16 tokens.
// Reads xa once (coalesced from global), writes lnb bf16 + lnm (routing).
// Saves one full xa read pass + one dispatch vs separate LN1/lnmean.
// ---------------------------------------------------------------------------
__global__ __launch_bounds__(256) void ln1mean_kernel(
    const float* __restrict__ xa, const float* __restrict__ g,
    const float* __restrict__ bb, __bf16* __restrict__ lnb,
    float* __restrict__ lnm) {
  __shared__ float part[4][256];
  int blk = blockIdx.x;  // 8*64
  int b = blk >> 6, r = blk & 63;
  int h0 = (r >> 3) << 3, w0 = (r & 7) << 3;
  int wave = threadIdx.x >> 6, l = threadIdx.x & 63;
  float ga = g[l], gb2 = g[l + 64], gc = g[l + 128], gd = g[l + 192];
  float ba = bb[l], bb2 = bb[l + 64], bc = bb[l + 128], bd = bb[l + 192];
  float a0 = 0.f, a1 = 0.f, a2 = 0.f, a3 = 0.f;
  for (int t = 0; t < 16; t++) {
    int p = wave * 16 + t;
    int h = h0 + (p >> 3), w = w0 + (p & 7);
    size_t tok = (size_t)(b * 4096 + h * 64 + w) * 256;
    const float* row = xa + tok;
    float v0 = row[l], v1 = row[l + 64], v2 = row[l + 128], v3 = row[l + 192];
    float s = v0 + v1 + v2 + v3;
#pragma unroll
    for (int off = 32; off; off >>= 1) s += __shfl_xor(s, off);
    float mu = s * (1.f / 256.f);
    float d0 = v0 - mu, d1 = v1 - mu, d2 = v2 - mu, d3 = v3 - mu;
    float sq = d0 * d0 + d1 * d1 + d2 * d2 + d3 * d3;
#pragma unroll
    for (int off = 32; off; off >>= 1) sq += __shfl_xor(sq, off);
    float rstd = rsqrtf(sq * (1.f / 256.f) + 1e-6f);
    float n0 = d0 * rstd, n1 = d1 * rstd, n2 = d2 * rstd, n3 = d3 * rstd;
    __bf16* o = lnb + tok;
    o[l]       = (__bf16)(n0 * ga + ba);
    o[l + 64]  = (__bf16)(n1 * gb2 + bb2);
    o[l + 128] = (__bf16)(n2 * gc + bc);
    o[l + 192] = (__bf16)(n3 * gd + bd);
    a0 += n0; a1 += n1; a2 += n2; a3 += n3;
  }
  part[wave][l] = a0; part[wave][l + 64] = a1;
  part[wave][l + 128] = a2; part[wave][l + 192] = a3;
  __syncthreads();
  if (wave == 0) {
    for (int ch = l; ch < 256; ch += 64) {
      float s2 = part[0][ch] + part[1][ch] + part[2][ch] + part[3][ch];
      lnm[(size_t)(b * 64 + r) * 256 + ch] = g[ch] * (s2 * (1.f / 64.f)) + bb[ch];
    }
  }
}

// ---------------------------------------------------------------------------
// LayerNorm over C=256, one wave per token, bf16 output (LN2)
// ---------------------------------------------------------------------------
__global__ __launch_bounds__(64) void ln_kernel(
    const float* __restrict__ in, const float* __restrict__ g,
    const float* __restrict__ bb, __bf16* __restrict__ out) {
  int t = blockIdx.x; int l = threadIdx.x;
  const float* p = in + (size_t)t * 256;
  float v0 = p[l], v1 = p[l + 64], v2 = p[l + 128], v3 = p[l + 192];
  float s = v0 + v1 + v2 + v3;
#pragma unroll
  for (int off = 32; off; off >>= 1) s += __shfl_xor(s, off);
  float mu = s * (1.f / 256.f);
  float d0 = v0 - mu, d1 = v1 - mu, d2 = v2 - mu, d3 = v3 - mu;
  float sq = d0 * d0 + d1 * d1 + d2 * d2 + d3 * d3;
#pragma unroll
  for (int off = 32; off; off >>= 1) sq += __shfl_xor(sq, off);
  float rstd = rsqrtf(sq * (1.f / 256.f) + 1e-6f);
  __bf16* o = out + (size_t)t * 256;
  o[l]       = (__bf16)(d0 * rstd * g[l]       + bb[l]);
  o[l + 64]  = (__bf16)(d1 * rstd * g[l + 64]  + bb[l + 64]);
  o[l + 128] = (__bf16)(d2 * rstd * g[l + 128] + bb[l + 128]);
  o[l + 192] = (__bf16)(d3 * rstd * g[l + 192] + bb[l + 192]);
}

// ---------------------------------------------------------------------------
// Weight prep: bf16-convert qkv_w [768][256], out_w [256][256] (already [N][K]),
// transpose+convert mlp_w1 [256][768]->[768][256], mlp_w2 [768][256]->[256][768]
// ---------------------------------------------------------------------------
__global__ __launch_bounds__(256) void wprep_kernel(
    const float* __restrict__ qkv_w, const float* __restrict__ out_w,
    const float* __restrict__ w1, const float* __restrict__ w2,
    __bf16* __restrict__ wq, __bf16* __restrict__ wo,
    __bf16* __restrict__ w1t, __bf16* __restrict__ w2t) {
  int i = blockIdx.x * 256 + threadIdx.x;
  if (i < 196608) wq[i] = (__bf16)qkv_w[i];
  if (i < 65536) wo[i] = (__bf16)out_w[i];
  if (i < 196608) {  // w1t[n][k] = w1[k][n], n<768, k<256
    int n = i >> 8, k2 = i & 255;
    w1t[i] = (__bf16)w1[k2 * 768 + n];
  }
  if (i < 196608) {  // w2t[n][k] = w2[k][n], n<256, k<768
    int n = i / 768, k2 = i % 768;
    w2t[i] = (__bf16)w2[k2 * 256 + n];
  }
}

// ---------------------------------------------------------------------------
// MFMA bf16 GEMM: C[row][col] = epi( sum_k A[row][k]*Bw[col][k] + bias[col] )
// A [M][K] bf16, Bw [N][K] bf16. 128x128 tile, BK=32, 4 waves (2x2 quadrants),
// global_load_lds width-16 staging, mfma_f32_16x16x32_bf16.
// EPI: 0 = scatter to q(fp32)/k,v(bf16) seq layout; 1 = fp32 res+val;
//      2 = gelu -> bf16; 3 = res+val written NCHW fp32 (fused transpose)
// ---------------------------------------------------------------------------
template <int EPI>
__global__ __launch_bounds__(256) void mfma_gemm(
    const __bf16* __restrict__ A, const __bf16* __restrict__ Bw,
    const float* __restrict__ bias, const float* __restrict__ res,
    float* __restrict__ out, __bf16* __restrict__ outb,
    float* __restrict__ qd, __bf16* __restrict__ kd, __bf16* __restrict__ vd,
    int N, int K, int row0) {
  __shared__ __bf16 Asl[128 * 32];
  __shared__ __bf16 Bsl[128 * 32];
  int tid = threadIdx.x;
  int lane = tid & 63, wave = tid >> 6;
  int m0 = blockIdx.y * 128, n0 = blockIdx.x * 128;
  int wr = (wave >> 1) * 64, wc = (wave & 1) * 64;

  f32x4 acc[4][4];
  f32x4 z = {0.f, 0.f, 0.f, 0.f};
#pragma unroll
  for (int i = 0; i < 4; i++)
#pragma unroll
    for (int j = 0; j < 4; j++) acc[i][j] = z;

  int srow = (lane >> 2);          // 0..15
  int skoff = (lane & 3) * 8;      // 0,8,16,24
  for (int k0 = 0; k0 < K; k0 += 32) {
#pragma unroll
    for (int j = 0; j < 2; j++) {
      int rbase = wave * 32 + j * 16;
      const __bf16* ga = A + (size_t)(m0 + rbase + srow) * K + k0 + skoff;
      const __bf16* gb = Bw + (size_t)(n0 + rbase + srow) * K + k0 + skoff;
      async_copy16(ga, &Asl[rbase * 32]);
      async_copy16(gb, &Bsl[rbase * 32]);
    }
    __syncthreads();
    bf16x8 af[4], bf[4];
#pragma unroll
    for (int t = 0; t < 4; t++) {
      af[t] = *(const bf16x8*)&Asl[(wr + t * 16 + (lane & 15)) * 32 + (lane >> 4) * 8];
      bf[t] = *(const bf16x8*)&Bsl[(wc + t * 16 + (lane & 15)) * 32 + (lane >> 4) * 8];
    }
#pragma unroll
    for (int ti = 0; ti < 4; ti++)
#pragma unroll
      for (int tj = 0; tj < 4; tj++)
        acc[ti][tj] = __builtin_amdgcn_mfma_f32_16x16x32_bf16(
            af[ti], bf[tj], acc[ti][tj], 0, 0, 0);
    __syncthreads();
  }
  // epilogue: C/D layout col=lane&15, row=(lane>>4)*4+reg
#pragma unroll
  for (int ti = 0; ti < 4; ti++) {
#pragma unroll
    for (int tj = 0; tj < 4; tj++) {
      int colg = n0 + wc + tj * 16 + (lane & 15);
      float bv = bias[colg];
#pragma unroll
      for (int reg = 0; reg < 4; reg++) {
        int rowg = m0 + wr + ti * 16 + (lane >> 4) * 4 + reg;
        float val = acc[ti][tj][reg] + bv;
        if (EPI == 0) {
          int tns = colg >> 8, cc = colg & 255, m = cc >> 5, d = cc & 31;
          int grow = row0 + rowg;
          int b = grow >> 12, hw = grow & 4095, h = hw >> 6, w = hw & 63;
          int r = ((h >> 3) << 3) | (w >> 3), s2 = ((h & 7) << 3) | (w & 7);
          size_t addr = (size_t)(b * 8 + m) * 131072 + r * 2048 + s2 * 32 + d;
          if (tns == 0) qd[addr] = val;
          else if (tns == 1) kd[addr] = (__bf16)val;
          else vd[addr] = (__bf16)val;
        } else if (EPI == 1) {
          out[(size_t)rowg * N + colg] = res[(size_t)rowg * N + colg] + val;
        } else if (EPI == 2) {
          outb[(size_t)rowg * N + colg] =
              (__bf16)(0.5f * val * (1.f + erff(val * 0.70710678118654752f)));
        } else {
          int grow = row0 + rowg;
          int b = grow >> 12, hw = grow & 4095;
          out[(size_t)(b * 256 + colg) * 4096 + hw] =
              res[(size_t)grow * 256 + colg] + val;
        }
      }
    }
  }
}

__global__ __launch_bounds__(256) void qkr_kernel(
    const float* __restrict__ lnm, const float* __restrict__ qkv_w,
    const float* __restrict__ qkv_b, float* __restrict__ qr,
    float* __restrict__ kr) {
  __shared__ float xm[256];
  int br = blockIdx.x, c = threadIdx.x;
  xm[c] = lnm[(size_t)br * 256 + c];
  __syncthreads();
  const float* wqp = qkv_w + (size_t)c * 256;
  const float* wkp = qkv_w + (size_t)(256 + c) * 256;
  float aq = 0.f, ak = 0.f;
  for (int k2 = 0; k2 < 256; k2++) {
    float xv = xm[k2];
    aq += wqp[k2] * xv; ak += wkp[k2] * xv;
  }
  qr[(size_t)br * 256 + c] = aq + qkv_b[c];
  kr[(size_t)br * 256 + c] = ak + qkv_b[256 + c];
}

// ---------------------------------------------------------------------------
// R2: a_r = q_r @ k_r^T per batch; top-4 regions per row (jax tie: lower idx)
// ---------------------------------------------------------------------------
__global__ __launch_bounds__(256) void routing_kernel(
    const float* __restrict__ qr, const float* __restrict__ kr,
    int* __restrict__ idxout) {
  __shared__ float Ar[64 * 64];
  int b = blockIdx.x; int tid = threadIdx.x;
  int i = tid >> 2, jg = tid & 3;
  const float* qrow = qr + (size_t)(b * 64 + i) * 256;
  for (int jj = 0; jj < 16; jj++) {
    int j = jg * 16 + jj;
    const float* krow = kr + (size_t)(b * 64 + j) * 256;
    float acc = 0.f;
    for (int c = 0; c < 256; c++) acc += qrow[c] * krow[c];
    Ar[i * 64 + j] = acc;
  }
  __syncthreads();
  if (tid < 64) {
    float v0 = -INFINITY, v1 = -INFINITY, v2 = -INFINITY, v3 = -INFINITY;
    int i0 = 0, i1 = 0, i2 = 0, i3 = 0;
    for (int j = 0; j < 64; j++) {
      float s = Ar[tid * 64 + j];
      if (s > v0)      { v3=v2;i3=i2; v2=v1;i2=i1; v1=v0;i1=i0; v0=s;i0=j; }
      else if (s > v1) { v3=v2;i3=i2; v2=v1;i2=i1; v1=s;i1=j; }
      else if (s > v2) { v3=v2;i3=i2; v2=s;i2=j; }
      else if (s > v3) { v3=s;i3=j; }
    }
    int* op = idxout + (b * 64 + tid) * 4;
    op[0] = i0; op[1] = i1; op[2] = i2; op[3] = i3;
  }
}

// ---------------------------------------------------------------------------
// Attention per (b,m,r): r8's proven config — 16-bit ballot radix-select,
// packed f32x2 scores, launch_bounds(256,2) = 124 VGPR, NO spill. FROZEN.
// ---------------------------------------------------------------------------
__global__ __launch_bounds__(256, 2) void attn_kernel(
    float* __restrict__ qio, const __bf16* __restrict__ kbuf,
    const __bf16* __restrict__ vbuf, const int* __restrict__ idx) {
  __shared__ __bf16 Ks[256 * 32];
  __shared__ __bf16 Vs[256 * 32];
  __shared__ float wbuf[4][4][32];
  __shared__ unsigned short cbuf[4][4][32];
  int blk = blockIdx.x; int r = blk & 63; int m = (blk >> 6) & 7; int b = blk >> 9;
  int tid = threadIdx.x;
  int lane = tid & 63, wave = tid >> 6;
  const int* ip = idx + (b * 64 + r) * 4;
  int rg0 = ip[0], rg1 = ip[1], rg2 = ip[2], rg3 = ip[3];
  size_t bm = (size_t)(b * 8 + m) * 131072;

  {
    int rgs[4] = {rg0, rg1, rg2, rg3};
    int s = tid >> 2, g8 = tid & 3;
#pragma unroll
    for (int t = 0; t < 4; t++) {
      const uint4* sk = (const uint4*)(kbuf + bm + rgs[t] * 2048);
      const uint4* sv = (const uint4*)(vbuf + bm + rgs[t] * 2048);
      int kk = (t << 6) | s;
      uint4 kw = sk[tid];
      uint4 vw = sv[tid];
      int dg0 = g8 * 2, dg1 = dg0 + 1;
      uint2 lo; lo.x = kw.x; lo.y = kw.y;
      uint2 hi; hi.x = kw.z; hi.y = kw.w;
      *(uint2*)&Ks[(kk << 5) + (((dg0 + (kk >> 1)) & 7) << 2)] = lo;
      *(uint2*)&Ks[(kk << 5) + (((dg1 + (kk >> 1)) & 7) << 2)] = hi;
      *(uint4*)&Vs[(kk << 5) + (g8 << 3)] = vw;
    }
  }
  __syncthreads();

  const float* qb = qio + bm + r * 2048;
  const float scale = 1.f / 16.f;  // C^-0.5

  for (int g = 0; g < 4; g++) {
    int row0 = (wave << 4) | (g << 2);
    f32x2 sc2[4][4];
    f32x2 z2 = {0.f, 0.f};
#pragma unroll
    for (int i = 0; i < 4; i++)
#pragma unroll
      for (int t = 0; t < 4; t++) sc2[i][t] = z2;
    const f32x2* qp0 = (const f32x2*)(qb + (row0 + 0) * 32);
    const f32x2* qp1 = (const f32x2*)(qb + (row0 + 1) * 32);
    const f32x2* qp2 = (const f32x2*)(qb + (row0 + 2) * 32);
    const f32x2* qp3 = (const f32x2*)(qb + (row0 + 3) * 32);
#pragma unroll
    for (int dg = 0; dg < 8; dg++) {
      f32x2 q0a = qp0[dg * 2], q0b = qp0[dg * 2 + 1];
      f32x2 q1a = qp1[dg * 2], q1b = qp1[dg * 2 + 1];
      f32x2 q2a = qp2[dg * 2], q2b = qp2[dg * 2 + 1];
      f32x2 q3a = qp3[dg * 2], q3b = qp3[dg * 2 + 1];
#pragma unroll
      for (int t = 0; t < 4; t++) {
        int kk = (t << 6) | lane;
        const unsigned* kp =
            (const unsigned*)&Ks[(kk << 5) | (((dg + (kk >> 1)) & 7) << 2)];
        unsigned lo = kp[0], hi = kp[1];
        f32x2 kxy, kzw;
        kxy.x = __uint_as_float(lo << 16);
        kxy.y = __uint_as_float(lo & 0xffff0000u);
        kzw.x = __uint_as_float(hi << 16);
        kzw.y = __uint_as_float(hi & 0xffff0000u);
        sc2[0][t] = sc2[0][t] + q0a * kxy + q0b * kzw;
        sc2[1][t] = sc2[1][t] + q1a * kxy + q1b * kzw;
        sc2[2][t] = sc2[2][t] + q2a * kxy + q2b * kzw;
        sc2[3][t] = sc2[3][t] + q3a * kxy + q3b * kzw;
      }
    }
    // horizontal add + scale, then 16-bit monotone key
    float sc[4][4];
    unsigned uk[4][4];
#pragma unroll
    for (int i = 0; i < 4; i++)
#pragma unroll
      for (int t = 0; t < 4; t++) {
        float v = (sc2[i][t].x + sc2[i][t].y) * scale;
        sc[i][t] = v;
        unsigned bu = __float_as_uint(v);
        uk[i][t] = (bu ^ (unsigned)(((int)bu >> 31) | 0x80000000)) >> 16;
      }
    unsigned p0 = 0, p1 = 0, p2 = 0, p3 = 0;
    for (int bit = 15; bit >= 0; --bit) {
      unsigned msk = 1u << bit;
      unsigned c0 = p0 | msk, c1 = p1 | msk, c2 = p2 | msk, c3 = p3 | msk;
      int n0 = __popcll(__ballot(uk[0][0] >= c0)) + __popcll(__ballot(uk[0][1] >= c0)) +
               __popcll(__ballot(uk[0][2] >= c0)) + __popcll(__ballot(uk[0][3] >= c0));
      int n1 = __popcll(__ballot(uk[1][0] >= c1)) + __popcll(__ballot(uk[1][1] >= c1)) +
               __popcll(__ballot(uk[1][2] >= c1)) + __popcll(__ballot(uk[1][3] >= c1));
      int n2 = __popcll(__ballot(uk[2][0] >= c2)) + __popcll(__ballot(uk[2][1] >= c2)) +
               __popcll(__ballot(uk[2][2] >= c2)) + __popcll(__ballot(uk[2][3] >= c2));
      int n3 = __popcll(__ballot(uk[3][0] >= c3)) + __popcll(__ballot(uk[3][1] >= c3)) +
               __popcll(__ballot(uk[3][2] >= c3)) + __popcll(__ballot(uk[3][3] >= c3));
      if (n0 >= 32) p0 = c0;
      if (n1 >= 32) p1 = c1;
      if (n2 >= 32) p2 = c2;
      if (n3 >= 32) p3 = c3;
    }
    unsigned pr[4] = {p0, p1, p2, p3};
#pragma unroll
    for (int i = 0; i < 4; i++) {
      unsigned T = pr[i];
      unsigned ub = T << 16;  // lower bound of the 16-bit tie class
      unsigned tb = (ub & 0x80000000u) ? (ub ^ 0x80000000u) : ~ub;
      float Tv = __uint_as_float(tb);
      unsigned long long gb[4], eb[4];
#pragma unroll
      for (int t = 0; t < 4; t++) {
        gb[t] = __ballot(uk[i][t] > T);
        eb[t] = __ballot(uk[i][t] == T);
      }
      int bg1 = __popcll(gb[0]), bg2 = bg1 + __popcll(gb[1]), bg3 = bg2 + __popcll(gb[2]);
      int cgt = bg3 + __popcll(gb[3]);
      int be1 = __popcll(eb[0]), be2 = be1 + __popcll(eb[1]), be3 = be2 + __popcll(eb[2]);
      int need = 32 - cgt;
      int bgs[4] = {0, bg1, bg2, bg3};
      int bes[4] = {0, be1, be2, be3};
#pragma unroll
      for (int t = 0; t < 4; t++) {
        int rgt = bgs[t] + __builtin_amdgcn_mbcnt_hi(
                               (unsigned)(gb[t] >> 32),
                               __builtin_amdgcn_mbcnt_lo((unsigned)gb[t], 0));
        int ret = bes[t] + __builtin_amdgcn_mbcnt_hi(
                               (unsigned)(eb[t] >> 32),
                               __builtin_amdgcn_mbcnt_lo((unsigned)eb[t], 0));
        bool isg = uk[i][t] > T;
        bool sel = isg || (uk[i][t] == T && ret < need);
        int slot = isg ? rgt : (cgt + ret);
        if (sel) {
          wbuf[wave][i][slot] = __expf(sc[i][t] - Tv);
          cbuf[wave][i][slot] = (unsigned short)((t << 6) | lane);
        }
      }
    }
#pragma unroll
    for (int i = 0; i < 4; i++) {
      int dd = lane & 31, half = lane >> 5;
      float acc = 0.f, wsum = 0.f;
#pragma unroll
      for (int it2 = 0; it2 < 16; it2++) {
        int sl = (half << 4) | it2;
        float wi = wbuf[wave][i][sl];
        int ci = cbuf[wave][i][sl];
        acc += wi * (float)Vs[(ci << 5) | dd];
        wsum += wi;
      }
      acc += __shfl_xor(acc, 32);
      wsum += __shfl_xor(wsum, 32);
      if (lane < 32) qio[bm + r * 2048 + (row0 + i) * 32 + dd] = acc / wsum;
    }
  }
}

// ---------------------------------------------------------------------------
// K6: t = seq2grid(attn_out) + dwconv5x5(v) + lepe_b, NHWC bf16 out.
// ---------------------------------------------------------------------------
__global__ __launch_bounds__(256) void lepe_kernel(
    const float* __restrict__ ao, const __bf16* __restrict__ v,
    const float* __restrict__ lw, const float* __restrict__ lb,
    __bf16* __restrict__ tout) {
  __shared__ float Ls[144][32];
  __shared__ float Ws[25][32];
  int blk = blockIdx.x;  // 8*8*64
  int b = blk >> 9, m = (blk >> 6) & 7, r = blk & 63;
  int h0 = (r >> 3) << 3, w0 = (r & 7) << 3;
  int tid = threadIdx.x, d = tid & 31;
  size_t bm = (size_t)(b * 8 + m) * 131072;
  for (int i = tid; i < 144 * 32; i += 256) {
    int pos = i >> 5, dd = i & 31;
    int hh = h0 + (pos / 12) - 2, ww = w0 + (pos % 12) - 2;
    float val = 0.f;
    if (hh >= 0 && hh < 64 && ww >= 0 && ww < 64) {
      int r2 = ((hh >> 3) << 3) | (ww >> 3), s2 = ((hh & 7) << 3) | (ww & 7);
      val = (float)v[bm + r2 * 2048 + s2 * 32 + dd];
    }
    Ls[pos][dd] = val;
  }
  for (int i = tid; i < 800; i += 256) {
    int tap = i >> 5, dd = i & 31;
    Ws[tap][dd] = lw[(m * 32 + dd) * 25 + tap];
  }
  __syncthreads();
  int c = m * 32 + d;
  float bias = lb[c];
  for (int j = 0; j < 8; j++) {
    int p = (tid >> 5) + (j << 3);
    int ph = p >> 3, pww = p & 7;
    float acc = bias;
#pragma unroll
    for (int dh = 0; dh < 5; dh++)
#pragma unroll
      for (int dw = 0; dw < 5; dw++)
        acc += Ls[(ph + dh) * 12 + (pww + dw)][d] * Ws[dh * 5 + dw][d];
    acc += ao[bm + r * 2048 + p * 32 + d];
    tout[((size_t)(b * 4096 + (h0 + ph) * 64 + (w0 + pww))) * 256 + c] =
        (__bf16)acc;
  }
}

extern "C" void kernel_launch(void* const* d_in, const int* in_sizes, int n_in,
                              void* d_out, int out_size, void* d_ws, size_t ws_size,
                              hipStream_t stream) {
  (void)in_sizes; (void)n_in; (void)out_size; (void)ws_size;
  const float* x      = (const float*)d_in[0];
  const float* pos_w  = (const float*)d_in[1];
  const float* pos_b  = (const float*)d_in[2];
  const float* ln1_g  = (const float*)d_in[3];
  const float* ln1_b  = (const float*)d_in[4];
  const float* qkv_w  = (const float*)d_in[5];
  const float* qkv_b  = (const float*)d_in[6];
  const float* lepe_w = (const float*)d_in[7];
  const float* lepe_b = (const float*)d_in[8];
  const float* out_w  = (const float*)d_in[9];
  const float* out_b  = (const float*)d_in[10];
  const float* ln2_g  = (const float*)d_in[11];
  const float* ln2_b  = (const float*)d_in[12];
  const float* mlp_w1 = (const float*)d_in[13];
  const float* mlp_b1 = (const float*)d_in[14];
  const float* mlp_w2 = (const float*)d_in[15];
  const float* mlp_b2 = (const float*)d_in[16];

  float* ws = (float*)d_ws;
  const size_t P = 8ull * 4096 * 256;  // 8.39M floats
  size_t off = 0;
  float* xa = ws + off; off += P;        // residual stream NHWC fp32
  float* q  = ws + off; off += P;        // q fp32 seq; also xt scratch
  __bf16* k = (__bf16*)(ws + off); off += P / 2;   // k bf16 seq
  __bf16* v = (__bf16*)(ws + off); off += P / 2;   // v bf16 seq
  __bf16* lnb = (__bf16*)(ws + off); off += P / 2; // bf16 activations
  __bf16* hb  = (__bf16*)(ws + off); off += 12582912; // MLP hidden [32768][768] bf16
  __bf16* wq  = (__bf16*)(ws + off); off += 98304;   // [768][256]
  __bf16* wo  = (__bf16*)(ws + off); off += 32768;   // [256][256]
  __bf16* w1t = (__bf16*)(ws + off); off += 98304;   // [768][256]
  __bf16* w2t = (__bf16*)(ws + off); off += 98304;   // [256][768]
  float* qr  = ws + off; off += 131072;
  float* kr  = ws + off; off += 131072;
  float* lnm = ws + off; off += 131072;
  int* ridx  = (int*)(ws + off);

  // 0) weight prep
  wprep_kernel<<<768, 256, 0, stream>>>(qkv_w, out_w, mlp_w1, mlp_w2,
                                        wq, wo, w1t, w2t);
  // 1) NCHW -> NHWC transpose of x into q (scratch)
  transpose_kernel<<<dim3(64, 4, 8), 256, 0, stream>>>(x, q, 256, 4096);
  // 2) pos dwconv + residual (r8 version)
  posconv_kernel<<<2048, 256, 0, stream>>>(q, pos_w, pos_b, xa);
  // 3) FUSED LN1 + region-mean (single xa read pass)
  ln1mean_kernel<<<512, 256, 0, stream>>>(xa, ln1_g, ln1_b, lnb, lnm);
  // 4) routing path, fp32-exact
  qkr_kernel<<<512, 256, 0, stream>>>(lnm, qkv_w, qkv_b, qr, kr);
  routing_kernel<<<8, 256, 0, stream>>>(qr, kr, ridx);
  // 5) qkv GEMM (MFMA bf16): q fp32, k/v bf16 seq layout
  mfma_gemm<0><<<dim3(6, 256), 256, 0, stream>>>(
      lnb, wq, qkv_b, nullptr, nullptr, nullptr, q, k, v, 768, 256, 0);
  // 6) sparse attention (writes into q)
  attn_kernel<<<4096, 256, 0, stream>>>(q, k, v, ridx);
  // 7) seq2grid + LEPE dwconv5x5 -> lnb (bf16 t)
  lepe_kernel<<<4096, 256, 0, stream>>>(q, v, lepe_w, lepe_b, lnb);
  // 8) out projection + residual into xa
  mfma_gemm<1><<<dim3(2, 256), 256, 0, stream>>>(
      lnb, wo, out_b, xa, xa, nullptr, nullptr, nullptr, nullptr, 256, 256, 0);
  // 9) LN2 -> bf16
  ln_kernel<<<32768, 64, 0, stream>>>(xa, ln2_g, ln2_b, lnb);
  // 10) MLP single pass; mlp2 writes d_out NCHW directly (fused transpose)
  mfma_gemm<2><<<dim3(6, 256), 256, 0, stream>>>(
      lnb, w1t, mlp_b1, nullptr, nullptr, hb, nullptr, nullptr, nullptr,
      768, 256, 0);
  mfma_gemm<3><<<dim3(2, 256), 256, 0, stream>>>(
      hb, w2t, mlp_b2, xa, (float*)d_out, nullptr, nullptr, nullptr, nullptr,
      256, 768, 0);
}